// Round 1
// baseline (6876.571 us; speedup 1.0000x reference)
//
#include <hip/hip_runtime.h>

typedef _Float16 h2_t __attribute__((ext_vector_type(2)));
typedef _Float16 h8_t __attribute__((ext_vector_type(8)));
typedef float    f4_t __attribute__((ext_vector_type(4)));
typedef unsigned short u16;

#define EMB   512
#define VOCAB 256
#define NB    64
#define NT    1024

__device__ __forceinline__ float dot2(unsigned a, unsigned b, float c) {
    return __builtin_amdgcn_fdot2(__builtin_bit_cast(h2_t, a),
                                  __builtin_bit_cast(h2_t, b), c, false);
}

__device__ __forceinline__ float fast_tanh(float z) {
    // 1 - 2/(e^{2z}+1): exact limits at +/-inf, ~1ulp elsewhere
    float e = __expf(2.0f * z);
    return 1.0f - 2.0f / (e + 1.0f);
}

// ---------------------------------------------------------------------------
// Prep: emb_proj = emb @ w_x^T + b_cell (f32), pack w_h -> f16 pairs, w_head -> f16
// grid: 256 proj blocks + 128 W2-pack blocks + 64 head-convert blocks
// ---------------------------------------------------------------------------
__global__ __launch_bounds__(256) void prep_kernel(
    const float* __restrict__ emb, const float* __restrict__ w_cell,
    const float* __restrict__ b_cell, const float* __restrict__ w_head,
    float* __restrict__ embp, unsigned* __restrict__ W2, u16* __restrict__ wh16)
{
    const int blk = blockIdx.x, tid = threadIdx.x;
    if (blk < 256) {
        const int v = blk;
        __shared__ __align__(16) float er[EMB];
        er[tid]       = emb[v * EMB + tid];
        er[tid + 256] = emb[v * EMB + 256 + tid];
        __syncthreads();
        const f4_t* er4 = (const f4_t*)er;
        #pragma unroll
        for (int half = 0; half < 2; ++half) {
            const int o = tid + half * 256;
            const f4_t* wr4 = (const f4_t*)(w_cell + (size_t)o * 1024); // w_x row o
            float s0 = 0.f, s1 = 0.f, s2 = 0.f, s3 = 0.f;
            #pragma unroll 8
            for (int e4 = 0; e4 < 128; ++e4) {
                f4_t w = wr4[e4], a = er4[e4];
                s0 = fmaf(w[0], a[0], s0);
                s1 = fmaf(w[1], a[1], s1);
                s2 = fmaf(w[2], a[2], s2);
                s3 = fmaf(w[3], a[3], s3);
            }
            embp[v * EMB + o] = (s0 + s1) + (s2 + s3) + b_cell[o];
        }
    } else if (blk < 384) {
        // pack w_h[o][e] (= w_cell[o*1024 + 512 + e]) into half2 pairs: W2[o*256 + p]
        const int base = (blk - 256) * 1024 + tid;
        #pragma unroll
        for (int i = 0; i < 4; ++i) {
            const int P = base + i * 256;          // 0..131071
            const int o = P >> 8, p = P & 255;
            h2_t v2;
            v2[0] = (_Float16)w_cell[(size_t)o * 1024 + 512 + 2 * p];
            v2[1] = (_Float16)w_cell[(size_t)o * 1024 + 512 + 2 * p + 1];
            W2[P] = __builtin_bit_cast(unsigned, v2);
        }
    } else {
        const int base = (blk - 384) * 2048 + tid;
        #pragma unroll
        for (int i = 0; i < 8; ++i) {
            const int idx = base + i * 256;        // 0..131071
            wh16[idx] = __builtin_bit_cast(u16, (_Float16)w_head[idx]);
        }
    }
}

// ---------------------------------------------------------------------------
// Recurrence: 64 blocks (one per batch) x 256 threads; thread owns rows o, o+256.
// w_h row: 256 half2-pairs = 64 uint4. 48 resident in VGPRs, 8+8 streamed from L2.
// h double-buffered in LDS (f16), read as b128 broadcasts.
// ---------------------------------------------------------------------------
__global__ __launch_bounds__(256, 1) void rnn_rec(
    const int* __restrict__ x, const float* __restrict__ h0,
    const unsigned* __restrict__ W2, const float* __restrict__ embp,
    u16* __restrict__ hs)
{
    const int b = blockIdx.x, tid = threadIdx.x;
    const int o1 = tid, o2 = tid + 256;

    __shared__ int xrow[NT];
    __shared__ uint4 hbuf[2][EMB / 8];   // 2 x 512 f16

    #pragma unroll
    for (int i = 0; i < 4; ++i) xrow[tid + i * 256] = x[b * NT + tid + i * 256];

    {
        _Float16* hw0 = (_Float16*)hbuf[0];
        hw0[o1] = (_Float16)h0[o1];
        hw0[o2] = (_Float16)h0[o2];
    }

    const uint4* __restrict__ W4 = (const uint4*)W2;   // row o = 64 uint4
    uint4 wr1[48], wr2[48];
    #pragma unroll
    for (int i = 0; i < 48; ++i) { wr1[i] = W4[o1 * 64 + i]; wr2[i] = W4[o2 * 64 + i]; }

    __syncthreads();

    u16 ph1 = 0, ph2 = 0;
    #pragma unroll 1
    for (int t = 0; t < NT; ++t) {
        const uint4* hc = (const uint4*)hbuf[t & 1];
        const int v = xrow[t];
        const int zo = v >> 20;                 // always 0; blocks LICM of tail loads
        const float xw1 = embp[v * EMB + o1];
        const float xw2 = embp[v * EMB + o2];

        if (t > 0) {                            // store prev h early: hides vmcnt drain
            hs[(((b << 10) + (t - 1)) << 9) + o1] = ph1;
            hs[(((b << 10) + (t - 1)) << 9) + o2] = ph2;
        }

        uint4 ua1[8], ua2[8];
        #pragma unroll
        for (int i = 0; i < 8; ++i) {
            ua1[i] = W4[o1 * 64 + 48 + i + zo];
            ua2[i] = W4[o2 * 64 + 48 + i + zo];
        }
        __builtin_amdgcn_sched_barrier(0);      // pin ua issue before resident dot

        float s1a = 0.f, s1b = 0.f, s2a = 0.f, s2b = 0.f;
        #pragma unroll
        for (int c = 0; c < 48; ++c) {
            uint4 h4 = hc[c];
            s1a = dot2(h4.x, wr1[c].x, s1a);
            s2a = dot2(h4.x, wr2[c].x, s2a);
            s1b = dot2(h4.y, wr1[c].y, s1b);
            s2b = dot2(h4.y, wr2[c].y, s2b);
            s1a = dot2(h4.z, wr1[c].z, s1a);
            s2a = dot2(h4.z, wr2[c].z, s2a);
            s1b = dot2(h4.w, wr1[c].w, s1b);
            s2b = dot2(h4.w, wr2[c].w, s2b);
        }
        #pragma unroll
        for (int i = 0; i < 8; ++i) {
            uint4 h4 = hc[48 + i];
            s1a = dot2(h4.x, ua1[i].x, s1a);
            s2a = dot2(h4.x, ua2[i].x, s2a);
            s1b = dot2(h4.y, ua1[i].y, s1b);
            s2b = dot2(h4.y, ua2[i].y, s2b);
            s1a = dot2(h4.z, ua1[i].z, s1a);
            s2a = dot2(h4.z, ua2[i].z, s2a);
            s1b = dot2(h4.w, ua1[i].w, s1b);
            s2b = dot2(h4.w, ua2[i].w, s2b);
        }
        __builtin_amdgcn_sched_barrier(0);      // ua regs dead before ub loads issue

        uint4 ub1[8], ub2[8];
        #pragma unroll
        for (int i = 0; i < 8; ++i) {
            ub1[i] = W4[o1 * 64 + 56 + i + zo];
            ub2[i] = W4[o2 * 64 + 56 + i + zo];
        }
        #pragma unroll
        for (int i = 0; i < 8; ++i) {
            uint4 h4 = hc[56 + i];
            s1a = dot2(h4.x, ub1[i].x, s1a);
            s2a = dot2(h4.x, ub2[i].x, s2a);
            s1b = dot2(h4.y, ub1[i].y, s1b);
            s2b = dot2(h4.y, ub2[i].y, s2b);
            s1a = dot2(h4.z, ub1[i].z, s1a);
            s2a = dot2(h4.z, ub2[i].z, s2a);
            s1b = dot2(h4.w, ub1[i].w, s1b);
            s2b = dot2(h4.w, ub2[i].w, s2b);
        }

        const float h1 = fast_tanh((s1a + s1b) + xw1);
        const float h2 = fast_tanh((s2a + s2b) + xw2);
        const _Float16 hh1 = (_Float16)h1, hh2 = (_Float16)h2;
        _Float16* hw = (_Float16*)hbuf[(t + 1) & 1];
        hw[o1] = hh1;
        hw[o2] = hh2;
        ph1 = __builtin_bit_cast(u16, hh1);
        ph2 = __builtin_bit_cast(u16, hh2);
        __syncthreads();
    }
    hs[(((b << 10) + (NT - 1)) << 9) + o1] = ph1;
    hs[(((b << 10) + (NT - 1)) << 9) + o2] = ph2;
}

// ---------------------------------------------------------------------------
// Head: out[bt][n] = hs[bt][:] @ w_head[n][:]^T + b_head[n], MFMA f16 16x16x32.
// Block: 64 bt-rows (A staged in padded LDS), 8 waves x 2 n-tiles, B-frags in regs.
// ---------------------------------------------------------------------------
__global__ __launch_bounds__(512, 2) void head_kernel(
    const u16* __restrict__ hs, const u16* __restrict__ wh16,
    const float* __restrict__ b_head, float* __restrict__ out)
{
    const int tid  = threadIdx.x;
    const int wave = tid >> 6, lane = tid & 63;
    const int l15  = lane & 15, q = lane >> 4;
    const int bt0  = blockIdx.x * 64;

    __shared__ __align__(16) u16 As[64][520];   // +8 halfs pad: breaks bank aliasing

    {   // stage 64x512 f16 tile
        const uint4* src = (const uint4*)(hs + (size_t)bt0 * EMB);
        #pragma unroll
        for (int i = 0; i < 8; ++i) {
            const int idx = tid + i * 512;       // 0..4095 uint4s
            const int row = idx >> 6, col8 = idx & 63;
            *(uint4*)&As[row][col8 * 8] = src[idx];
        }
    }

    // B fragments: wave owns n-tiles {2*wave, 2*wave+1}; B[k][n] = w_head[n][k]
    uint4 bn[16][2];
    #pragma unroll
    for (int i = 0; i < 16; ++i)
        #pragma unroll
        for (int j = 0; j < 2; ++j) {
            const int n = wave * 32 + j * 16 + l15;
            const int k = i * 32 + q * 8;
            bn[i][j] = *(const uint4*)(wh16 + (size_t)n * EMB + k);
        }
    __syncthreads();

    #pragma unroll 1
    for (int mt = 0; mt < 4; ++mt) {
        f4_t acc0 = {0.f, 0.f, 0.f, 0.f}, acc1 = {0.f, 0.f, 0.f, 0.f};
        const int row = mt * 16 + l15;
        #pragma unroll
        for (int i = 0; i < 16; ++i) {
            const int k = i * 32 + q * 8;
            h8_t a = *(const h8_t*)&As[row][k];
            acc0 = __builtin_amdgcn_mfma_f32_16x16x32_f16(
                a, __builtin_bit_cast(h8_t, bn[i][0]), acc0, 0, 0, 0);
            acc1 = __builtin_amdgcn_mfma_f32_16x16x32_f16(
                a, __builtin_bit_cast(h8_t, bn[i][1]), acc1, 0, 0, 0);
        }
        #pragma unroll
        for (int j = 0; j < 2; ++j) {
            const int n = wave * 32 + j * 16 + l15;
            const float bh = b_head[n];
            const f4_t av = j ? acc1 : acc0;
            #pragma unroll
            for (int r = 0; r < 4; ++r) {
                const int orow = bt0 + mt * 16 + q * 4 + r;   // D: row=q*4+r, col=l15
                out[(size_t)orow * VOCAB + n] = av[r] + bh;
            }
        }
    }
}

extern "C" void kernel_launch(void* const* d_in, const int* in_sizes, int n_in,
                              void* d_out, int out_size, void* d_ws, size_t ws_size,
                              hipStream_t stream) {
    (void)in_sizes; (void)n_in; (void)out_size; (void)ws_size;
    const int*   x      = (const int*)  d_in[0];
    const float* emb    = (const float*)d_in[1];
    const float* w_cell = (const float*)d_in[2];
    const float* b_cell = (const float*)d_in[3];
    const float* w_head = (const float*)d_in[4];
    const float* b_head = (const float*)d_in[5];
    const float* h0     = (const float*)d_in[6];
    float* out = (float*)d_out;

    char* ws = (char*)d_ws;
    float*    embp = (float*)   (ws);                 // 256*512*4 = 512 KB
    unsigned* W2   = (unsigned*)(ws + 524288);        // 512*256*4 = 512 KB
    u16*      wh16 = (u16*)     (ws + 1048576);       // 256*512*2 = 256 KB
    u16*      hs   = (u16*)     (ws + 1310720);       // 64*1024*512*2 = 64 MB

    prep_kernel<<<dim3(448), dim3(256), 0, stream>>>(emb, w_cell, b_cell, w_head,
                                                     embp, W2, wh16);
    rnn_rec<<<dim3(NB), dim3(256), 0, stream>>>(x, h0, W2, embp, hs);
    head_kernel<<<dim3((NB * NT) / 64), dim3(512), 0, stream>>>(hs, wh16, b_head, out);
}

// Round 2
// 5895.686 us; speedup vs baseline: 1.1664x; 1.1664x over previous
//
#include <hip/hip_runtime.h>

typedef _Float16 h2_t __attribute__((ext_vector_type(2)));
typedef _Float16 h8_t __attribute__((ext_vector_type(8)));
typedef float    f4_t __attribute__((ext_vector_type(4)));
typedef unsigned short u16;

#define EMB   512
#define VOCAB 256
#define NB    64
#define NT    1024

__device__ __forceinline__ float fast_tanh(float z) {
    // 1 - 2/(e^{2z}+1): exact limits at +/-inf, ~1ulp elsewhere
    float e = __expf(2.0f * z);
    return 1.0f - 2.0f / (e + 1.0f);
}

// ---------------------------------------------------------------------------
// Prep: emb_proj = emb @ w_x^T + b_cell (f32), pack w_h -> f16, w_head -> f16
// ---------------------------------------------------------------------------
__global__ __launch_bounds__(256) void prep_kernel(
    const float* __restrict__ emb, const float* __restrict__ w_cell,
    const float* __restrict__ b_cell, const float* __restrict__ w_head,
    float* __restrict__ embp, unsigned* __restrict__ W2, u16* __restrict__ wh16)
{
    const int blk = blockIdx.x, tid = threadIdx.x;
    if (blk < 256) {
        const int v = blk;
        __shared__ __align__(16) float er[EMB];
        er[tid]       = emb[v * EMB + tid];
        er[tid + 256] = emb[v * EMB + 256 + tid];
        __syncthreads();
        const f4_t* er4 = (const f4_t*)er;
        #pragma unroll
        for (int half = 0; half < 2; ++half) {
            const int o = tid + half * 256;
            const f4_t* wr4 = (const f4_t*)(w_cell + (size_t)o * 1024); // w_x row o
            float s0 = 0.f, s1 = 0.f, s2 = 0.f, s3 = 0.f;
            #pragma unroll 8
            for (int e4 = 0; e4 < 128; ++e4) {
                f4_t w = wr4[e4], a = er4[e4];
                s0 = fmaf(w[0], a[0], s0);
                s1 = fmaf(w[1], a[1], s1);
                s2 = fmaf(w[2], a[2], s2);
                s3 = fmaf(w[3], a[3], s3);
            }
            embp[v * EMB + o] = (s0 + s1) + (s2 + s3) + b_cell[o];
        }
    } else if (blk < 384) {
        // pack w_h[o][e] (= w_cell[o*1024 + 512 + e]) into f16: W2 as u16[o*512+e]
        const int base = (blk - 256) * 1024 + tid;
        #pragma unroll
        for (int i = 0; i < 4; ++i) {
            const int P = base + i * 256;          // 0..131071 (pairs)
            const int o = P >> 8, p = P & 255;
            h2_t v2;
            v2[0] = (_Float16)w_cell[(size_t)o * 1024 + 512 + 2 * p];
            v2[1] = (_Float16)w_cell[(size_t)o * 1024 + 512 + 2 * p + 1];
            W2[P] = __builtin_bit_cast(unsigned, v2);
        }
    } else {
        const int base = (blk - 384) * 2048 + tid;
        #pragma unroll
        for (int i = 0; i < 8; ++i) {
            const int idx = base + i * 256;        // 0..131071
            wh16[idx] = __builtin_bit_cast(u16, (_Float16)w_head[idx]);
        }
    }
}

// ---------------------------------------------------------------------------
// Recurrence, transposed MFMA form: per step, h_new^T[512 x 16] = w_h x h^T.
// 4 blocks x 512 threads; block owns 16 batches (the MFMA N dimension).
// A-operand = w_h, RESIDENT in AGPRs: wave owns 4 m-tiles -> 256 regs/lane.
// B-operand = h^T from double-buffered LDS: 16 ds_read_b128 per wave per step
// (minimal operand feed). C layout row=quad*4+r, col=lane&15 (HW-verified R1).
// ---------------------------------------------------------------------------
__global__ __launch_bounds__(512, 1) void rnn_rec(
    const int* __restrict__ x, const float* __restrict__ h0,
    const u16* __restrict__ whf, const float* __restrict__ embp,
    u16* __restrict__ hs)
{
    const int tid  = threadIdx.x;
    const int wave = tid >> 6, lane = tid & 63;
    const int n    = lane & 15, quad = lane >> 4;   // n = batch-in-block
    const int b0   = blockIdx.x * 16;

    __shared__ __align__(16) u16 hbuf[2][16][520];  // +8 pad: conflict-free, 16B-aligned

    {   // h0 broadcast to all 16 batch rows of buffer 0
        const _Float16 hv = (_Float16)h0[tid];
        const u16 u = __builtin_bit_cast(u16, hv);
        #pragma unroll
        for (int nn = 0; nn < 16; ++nn) hbuf[0][nn][tid] = u;
    }

    // Resident A fragments: Af[i][s] = w_h rows (wave*4+i)*16+n, k = s*32+quad*8..+7
    h8_t Af[4][16];
    #pragma unroll
    for (int i = 0; i < 4; ++i)
        #pragma unroll
        for (int s = 0; s < 16; ++s)
            Af[i][s] = *(const h8_t*)&whf[(size_t)(((wave << 2) + i) * 16 + n) * EMB
                                          + s * 32 + quad * 8];

    const int* xp  = x  + (size_t)(b0 + n) * NT;
    u16*       hsp = hs + (size_t)(b0 + n) * NT * EMB;

    __syncthreads();

    uint2 hv4[4];
    #pragma unroll 1
    for (int t = 0; t < NT; ++t) {
        const int v = xp[t];                        // token for this lane's batch

        if (t > 0) {                                // deferred global h-store (t-1)
            #pragma unroll
            for (int i = 0; i < 4; ++i)
                *(uint2*)&hsp[(size_t)(t - 1) * EMB + ((wave << 2) + i) * 16
                              + (quad << 2)] = hv4[i];
        }

        f4_t xwv[4];                                // xw gather, consumed at epilogue
        #pragma unroll
        for (int i = 0; i < 4; ++i)
            xwv[i] = *(const f4_t*)&embp[(size_t)v * EMB + ((wave << 2) + i) * 16
                                         + (quad << 2)];

        const u16 (*hb)[520] = hbuf[t & 1];
        f4_t acc[4];
        #pragma unroll
        for (int i = 0; i < 4; ++i) acc[i] = (f4_t){0.f, 0.f, 0.f, 0.f};

        #pragma unroll
        for (int s = 0; s < 16; ++s) {
            const h8_t bf = *(const h8_t*)&hb[n][s * 32 + quad * 8];
            #pragma unroll
            for (int i = 0; i < 4; ++i)
                acc[i] = __builtin_amdgcn_mfma_f32_16x16x32_f16(Af[i][s], bf,
                                                                acc[i], 0, 0, 0);
        }

        u16 (*hw)[520] = hbuf[(t + 1) & 1];
        #pragma unroll
        for (int i = 0; i < 4; ++i) {
            h2_t lo, hi;
            lo[0] = (_Float16)fast_tanh(acc[i][0] + xwv[i][0]);
            lo[1] = (_Float16)fast_tanh(acc[i][1] + xwv[i][1]);
            hi[0] = (_Float16)fast_tanh(acc[i][2] + xwv[i][2]);
            hi[1] = (_Float16)fast_tanh(acc[i][3] + xwv[i][3]);
            uint2 pk;
            pk.x = __builtin_bit_cast(unsigned, lo);
            pk.y = __builtin_bit_cast(unsigned, hi);
            *(uint2*)&hw[n][((wave << 2) + i) * 16 + (quad << 2)] = pk;
            hv4[i] = pk;
        }
        __syncthreads();
    }

    #pragma unroll
    for (int i = 0; i < 4; ++i)
        *(uint2*)&hsp[(size_t)(NT - 1) * EMB + ((wave << 2) + i) * 16
                      + (quad << 2)] = hv4[i];
}

// ---------------------------------------------------------------------------
// Head: out[bt][n] = hs[bt][:] @ w_head[n][:]^T + b_head[n], MFMA f16 16x16x32.
// ---------------------------------------------------------------------------
__global__ __launch_bounds__(512, 2) void head_kernel(
    const u16* __restrict__ hs, const u16* __restrict__ wh16,
    const float* __restrict__ b_head, float* __restrict__ out)
{
    const int tid  = threadIdx.x;
    const int wave = tid >> 6, lane = tid & 63;
    const int l15  = lane & 15, q = lane >> 4;
    const int bt0  = blockIdx.x * 64;

    __shared__ __align__(16) u16 As[64][520];   // +8 halfs pad: breaks bank aliasing

    {   // stage 64x512 f16 tile
        const uint4* src = (const uint4*)(hs + (size_t)bt0 * EMB);
        #pragma unroll
        for (int i = 0; i < 8; ++i) {
            const int idx = tid + i * 512;       // 0..4095 uint4s
            const int row = idx >> 6, col8 = idx & 63;
            *(uint4*)&As[row][col8 * 8] = src[idx];
        }
    }

    // B fragments: wave owns n-tiles {2*wave, 2*wave+1}; B[k][n] = w_head[n][k]
    uint4 bn[16][2];
    #pragma unroll
    for (int i = 0; i < 16; ++i)
        #pragma unroll
        for (int j = 0; j < 2; ++j) {
            const int n = wave * 32 + j * 16 + l15;
            const int k = i * 32 + q * 8;
            bn[i][j] = *(const uint4*)(wh16 + (size_t)n * EMB + k);
        }
    __syncthreads();

    #pragma unroll 1
    for (int mt = 0; mt < 4; ++mt) {
        f4_t acc0 = {0.f, 0.f, 0.f, 0.f}, acc1 = {0.f, 0.f, 0.f, 0.f};
        const int row = mt * 16 + l15;
        #pragma unroll
        for (int i = 0; i < 16; ++i) {
            const int k = i * 32 + q * 8;
            h8_t a = *(const h8_t*)&As[row][k];
            acc0 = __builtin_amdgcn_mfma_f32_16x16x32_f16(
                a, __builtin_bit_cast(h8_t, bn[i][0]), acc0, 0, 0, 0);
            acc1 = __builtin_amdgcn_mfma_f32_16x16x32_f16(
                a, __builtin_bit_cast(h8_t, bn[i][1]), acc1, 0, 0, 0);
        }
        #pragma unroll
        for (int j = 0; j < 2; ++j) {
            const int n = wave * 32 + j * 16 + l15;
            const float bh = b_head[n];
            const f4_t av = j ? acc1 : acc0;
            #pragma unroll
            for (int r = 0; r < 4; ++r) {
                const int orow = bt0 + mt * 16 + q * 4 + r;   // D: row=q*4+r, col=l15
                out[(size_t)orow * VOCAB + n] = av[r] + bh;
            }
        }
    }
}

extern "C" void kernel_launch(void* const* d_in, const int* in_sizes, int n_in,
                              void* d_out, int out_size, void* d_ws, size_t ws_size,
                              hipStream_t stream) {
    (void)in_sizes; (void)n_in; (void)out_size; (void)ws_size;
    const int*   x      = (const int*)  d_in[0];
    const float* emb    = (const float*)d_in[1];
    const float* w_cell = (const float*)d_in[2];
    const float* b_cell = (const float*)d_in[3];
    const float* w_head = (const float*)d_in[4];
    const float* b_head = (const float*)d_in[5];
    const float* h0     = (const float*)d_in[6];
    float* out = (float*)d_out;

    char* ws = (char*)d_ws;
    float*    embp = (float*)   (ws);                 // 256*512*4 = 512 KB
    unsigned* W2   = (unsigned*)(ws + 524288);        // 512*256*4 = 512 KB (f16 w_h)
    u16*      wh16 = (u16*)     (ws + 1048576);       // 256*512*2 = 256 KB
    u16*      hs   = (u16*)     (ws + 1310720);       // 64*1024*512*2 = 64 MB

    prep_kernel<<<dim3(448), dim3(256), 0, stream>>>(emb, w_cell, b_cell, w_head,
                                                     embp, W2, wh16);
    rnn_rec<<<dim3(4), dim3(512), 0, stream>>>(x, h0, (const u16*)W2, embp, hs);
    head_kernel<<<dim3((NB * NT) / 64), dim3(512), 0, stream>>>(hs, wh16, b_head, out);
}

// Round 4
// 5299.371 us; speedup vs baseline: 1.2976x; 1.1125x over previous
//
#include <hip/hip_runtime.h>

typedef _Float16 h2_t __attribute__((ext_vector_type(2)));
typedef _Float16 h8_t __attribute__((ext_vector_type(8)));
typedef float    f4_t __attribute__((ext_vector_type(4)));
typedef unsigned short u16;

#define EMB   512
#define VOCAB 256
#define NB    64
#define NT    1024

__device__ __forceinline__ float fast_tanh(float z) {
    // 1 - 2/(e^{2z}+1): exact limits at +/-inf, ~1ulp elsewhere
    float e = __expf(2.0f * z);
    return 1.0f - 2.0f / (e + 1.0f);
}

__device__ __forceinline__ unsigned pk2(float a, float b) {
    return __builtin_bit_cast(unsigned, __builtin_amdgcn_cvt_pkrtz(a, b));
}

// ---------------------------------------------------------------------------
// Prep: emb_proj = emb @ w_x^T + b_cell (f32), pack w_h -> f16, w_head -> f16
// ---------------------------------------------------------------------------
__global__ __launch_bounds__(256) void prep_kernel(
    const float* __restrict__ emb, const float* __restrict__ w_cell,
    const float* __restrict__ b_cell, const float* __restrict__ w_head,
    float* __restrict__ embp, unsigned* __restrict__ W2, u16* __restrict__ wh16)
{
    const int blk = blockIdx.x, tid = threadIdx.x;
    if (blk < 256) {
        const int v = blk;
        __shared__ __align__(16) float er[EMB];
        er[tid]       = emb[v * EMB + tid];
        er[tid + 256] = emb[v * EMB + 256 + tid];
        __syncthreads();
        const f4_t* er4 = (const f4_t*)er;
        #pragma unroll
        for (int half = 0; half < 2; ++half) {
            const int o = tid + half * 256;
            const f4_t* wr4 = (const f4_t*)(w_cell + (size_t)o * 1024); // w_x row o
            float s0 = 0.f, s1 = 0.f, s2 = 0.f, s3 = 0.f;
            #pragma unroll 8
            for (int e4 = 0; e4 < 128; ++e4) {
                f4_t w = wr4[e4], a = er4[e4];
                s0 = fmaf(w[0], a[0], s0);
                s1 = fmaf(w[1], a[1], s1);
                s2 = fmaf(w[2], a[2], s2);
                s3 = fmaf(w[3], a[3], s3);
            }
            embp[v * EMB + o] = (s0 + s1) + (s2 + s3) + b_cell[o];
        }
    } else if (blk < 384) {
        // pack w_h[o][e] (= w_cell[o*1024 + 512 + e]) into f16: W2 as u16[o*512+e]
        const int base = (blk - 256) * 1024 + tid;
        #pragma unroll
        for (int i = 0; i < 4; ++i) {
            const int P = base + i * 256;          // 0..131071 (pairs)
            const int o = P >> 8, p = P & 255;
            h2_t v2;
            v2[0] = (_Float16)w_cell[(size_t)o * 1024 + 512 + 2 * p];
            v2[1] = (_Float16)w_cell[(size_t)o * 1024 + 512 + 2 * p + 1];
            W2[P] = __builtin_bit_cast(unsigned, v2);
        }
    } else {
        const int base = (blk - 384) * 2048 + tid;
        #pragma unroll
        for (int i = 0; i < 8; ++i) {
            const int idx = base + i * 256;        // 0..131071
            wh16[idx] = __builtin_bit_cast(u16, (_Float16)w_head[idx]);
        }
    }
}

// ---------------------------------------------------------------------------
// Recurrence, transposed MFMA form: per step, h_new^T[512 x 16] = w_h x h^T.
// 4 blocks x 512 threads; block owns 16 batches (MFMA N dim).
// A = w_h resident in AGPRs (4 m-tiles x 16 k-slabs per wave = 256 regs/lane).
// h lives in LDS in *MFMA-B-fragment order*: octet (e>>5)*64 + ((e>>3)&3)*16 + n
// -> reads are stride-1 ds_read_b128 (conflict-free), writes uniform 4/bank.
// Barrier = raw "s_waitcnt lgkmcnt(0); s_barrier": NO vmcnt drain, so hs
// stores are fire-and-forget and the embp prefetch stays in flight across it.
// Token prefetched 2 steps ahead; xw gather 1 step ahead, used as MFMA C-init.
// ---------------------------------------------------------------------------
__global__ __launch_bounds__(512, 1) void rnn_rec(
    const int* __restrict__ x, const float* __restrict__ h0,
    const u16* __restrict__ whf, const float* __restrict__ embp,
    u16* __restrict__ hs)
{
    const int tid  = threadIdx.x;
    const int wave = tid >> 6, lane = tid & 63;
    const int n    = lane & 15, quad = lane >> 4;   // n = batch-in-block
    const int b0   = blockIdx.x * 16;

    __shared__ __align__(16) u16 hbuf[2][8192];     // B-frag order, 2 x 16 KB

    {   // h0 -> buffer 0, all 16 batch columns
        const u16 u = __builtin_bit_cast(u16, (_Float16)h0[tid]);
        const int e = tid;
        const int ob = ((e >> 5) * 64 + ((e >> 3) & 3) * 16) * 8 + (e & 7);
        #pragma unroll
        for (int nn = 0; nn < 16; ++nn) hbuf[0][ob + nn * 8] = u;
    }

    // Resident A fragments: rows m = I*16+n, k = s*32 + quad*8 .. +7  (I=wave*4+i)
    h8_t Af[4][16];
    #pragma unroll
    for (int i = 0; i < 4; ++i)
        #pragma unroll
        for (int s = 0; s < 16; ++s)
            Af[i][s] = *(const h8_t*)&whf[(size_t)(((wave << 2) + i) * 16 + n) * EMB
                                          + s * 32 + quad * 8];

    const int* xp  = x  + (size_t)(b0 + n) * NT;
    u16*       hsp = hs + (size_t)(b0 + n) * NT * EMB;

    int eofs[4], wofs[4];
    #pragma unroll
    for (int i = 0; i < 4; ++i) {
        const int I = (wave << 2) + i;
        eofs[i] = I * 16 + (quad << 2);                       // e-offset of acc[i]
        const int qq = (2 * I + (quad >> 1)) & 3;
        wofs[i] = ((I >> 1) * 64 + qq * 16 + n) * 8 + (quad & 1) * 4;
    }

    __syncthreads();

    int vB = xp[0];
    f4_t xw_cur[4];
    #pragma unroll
    for (int i = 0; i < 4; ++i)
        xw_cur[i] = *(const f4_t*)&embp[(size_t)vB * EMB + eofs[i]];
    vB = xp[1];

    #pragma unroll 1
    for (int t = 0; t < NT; ++t) {
        const int vC = xp[(t + 2 < NT) ? t + 2 : NT - 1];     // token t+2 (clamped)
        f4_t xw_next[4];                                      // xw for t+1, in flight
        #pragma unroll
        for (int i = 0; i < 4; ++i)
            xw_next[i] = *(const f4_t*)&embp[(size_t)vB * EMB + eofs[i]];

        const u16* hb = &hbuf[t & 1][0];
        f4_t acc[4];
        #pragma unroll
        for (int i = 0; i < 4; ++i) acc[i] = xw_cur[i];       // xw as C-init

        #pragma unroll
        for (int s = 0; s < 16; ++s) {
            const h8_t bf = *(const h8_t*)&hb[s * 512 + lane * 8];
            #pragma unroll
            for (int i = 0; i < 4; ++i)
                acc[i] = __builtin_amdgcn_mfma_f32_16x16x32_f16(Af[i][s], bf,
                                                                acc[i], 0, 0, 0);
        }

        u16* hw = &hbuf[(t + 1) & 1][0];
        #pragma unroll
        for (int i = 0; i < 4; ++i) {
            const f4_t a = acc[i];
            uint2 pk;
            pk.x = pk2(fast_tanh(a[0]), fast_tanh(a[1]));
            pk.y = pk2(fast_tanh(a[2]), fast_tanh(a[3]));
            *(uint2*)&hw[wofs[i]] = pk;                       // LDS, B-frag order
            *(uint2*)&hsp[(size_t)t * EMB + eofs[i]] = pk;    // global, no drain
        }

        vB = vC;
        #pragma unroll
        for (int i = 0; i < 4; ++i) xw_cur[i] = xw_next[i];

        // LDS-only barrier: deliberately NO vmcnt drain (hs stores/gathers fly on)
        asm volatile("s_waitcnt lgkmcnt(0)\n\ts_barrier" ::: "memory");
    }
}

// ---------------------------------------------------------------------------
// Head: out[bt][n] = hs[bt][:] @ w_head[n][:]^T + b_head[n], MFMA f16 16x16x32.
// ---------------------------------------------------------------------------
__global__ __launch_bounds__(512, 2) void head_kernel(
    const u16* __restrict__ hs, const u16* __restrict__ wh16,
    const float* __restrict__ b_head, float* __restrict__ out)
{
    const int tid  = threadIdx.x;
    const int wave = tid >> 6, lane = tid & 63;
    const int l15  = lane & 15, q = lane >> 4;
    const int bt0  = blockIdx.x * 64;

    __shared__ __align__(16) u16 As[64][520];   // +8 halfs pad: breaks bank aliasing

    {   // stage 64x512 f16 tile
        const uint4* src = (const uint4*)(hs + (size_t)bt0 * EMB);
        #pragma unroll
        for (int i = 0; i < 8; ++i) {
            const int idx = tid + i * 512;       // 0..4095 uint4s
            const int row = idx >> 6, col8 = idx & 63;
            *(uint4*)&As[row][col8 * 8] = src[idx];
        }
    }

    // B fragments: wave owns n-tiles {2*wave, 2*wave+1}; B[k][n] = w_head[n][k]
    uint4 bn[16][2];
    #pragma unroll
    for (int i = 0; i < 16; ++i)
        #pragma unroll
        for (int j = 0; j < 2; ++j) {
            const int n = wave * 32 + j * 16 + l15;
            const int k = i * 32 + q * 8;
            bn[i][j] = *(const uint4*)(wh16 + (size_t)n * EMB + k);
        }
    __syncthreads();

    #pragma unroll 1
    for (int mt = 0; mt < 4; ++mt) {
        f4_t acc0 = {0.f, 0.f, 0.f, 0.f}, acc1 = {0.f, 0.f, 0.f, 0.f};
        const int row = mt * 16 + l15;
        #pragma unroll
        for (int i = 0; i < 16; ++i) {
            const int k = i * 32 + q * 8;
            h8_t a = *(const h8_t*)&As[row][k];
            acc0 = __builtin_amdgcn_mfma_f32_16x16x32_f16(
                a, __builtin_bit_cast(h8_t, bn[i][0]), acc0, 0, 0, 0);
            acc1 = __builtin_amdgcn_mfma_f32_16x16x32_f16(
                a, __builtin_bit_cast(h8_t, bn[i][1]), acc1, 0, 0, 0);
        }
        #pragma unroll
        for (int j = 0; j < 2; ++j) {
            const int n = wave * 32 + j * 16 + l15;
            const float bh = b_head[n];
            const f4_t av = j ? acc1 : acc0;
            #pragma unroll
            for (int r = 0; r < 4; ++r) {
                const int orow = bt0 + mt * 16 + q * 4 + r;   // D: row=q*4+r, col=l15
                out[(size_t)orow * VOCAB + n] = av[r] + bh;
            }
        }
    }
}

extern "C" void kernel_launch(void* const* d_in, const int* in_sizes, int n_in,
                              void* d_out, int out_size, void* d_ws, size_t ws_size,
                              hipStream_t stream) {
    (void)in_sizes; (void)n_in; (void)out_size; (void)ws_size;
    const int*   x      = (const int*)  d_in[0];
    const float* emb    = (const float*)d_in[1];
    const float* w_cell = (const float*)d_in[2];
    const float* b_cell = (const float*)d_in[3];
    const float* w_head = (const float*)d_in[4];
    const float* b_head = (const float*)d_in[5];
    const float* h0     = (const float*)d_in[6];
    float* out = (float*)d_out;

    char* ws = (char*)d_ws;
    float*    embp = (float*)   (ws);                 // 256*512*4 = 512 KB
    unsigned* W2   = (unsigned*)(ws + 524288);        // 512*256*4 = 512 KB (f16 w_h)
    u16*      wh16 = (u16*)     (ws + 1048576);       // 256*512*2 = 256 KB
    u16*      hs   = (u16*)     (ws + 1310720);       // 64*1024*512*2 = 64 MB

    prep_kernel<<<dim3(448), dim3(256), 0, stream>>>(emb, w_cell, b_cell, w_head,
                                                     embp, W2, wh16);
    rnn_rec<<<dim3(4), dim3(512), 0, stream>>>(x, h0, (const u16*)W2, embp, hs);
    head_kernel<<<dim3((NB * NT) / 64), dim3(512), 0, stream>>>(hs, wh16, b_head, out);
}

// Round 5
// 3254.997 us; speedup vs baseline: 2.1126x; 1.6281x over previous
//
#include <hip/hip_runtime.h>

typedef _Float16 h2_t __attribute__((ext_vector_type(2)));
typedef _Float16 h8_t __attribute__((ext_vector_type(8)));
typedef float    f4_t __attribute__((ext_vector_type(4)));
typedef unsigned short u16;

#define EMB   512
#define VOCAB 256
#define NB    64
#define NT    1024

__device__ __forceinline__ float fast_tanh(float z) {
    float e = __expf(2.0f * z);
    return 1.0f - 2.0f / (e + 1.0f);
}

__device__ __forceinline__ unsigned pk2(float a, float b) {
    return __builtin_bit_cast(unsigned, __builtin_amdgcn_cvt_pkrtz(a, b));
}

// ---------------------------------------------------------------------------
// Prep: emb_proj = emb @ w_x^T + b_cell (f32), pack w_h -> f16, w_head -> f16
// ---------------------------------------------------------------------------
__global__ __launch_bounds__(256) void prep_kernel(
    const float* __restrict__ emb, const float* __restrict__ w_cell,
    const float* __restrict__ b_cell, const float* __restrict__ w_head,
    float* __restrict__ embp, unsigned* __restrict__ W2, u16* __restrict__ wh16)
{
    const int blk = blockIdx.x, tid = threadIdx.x;
    if (blk < 256) {
        const int v = blk;
        __shared__ __align__(16) float er[EMB];
        er[tid]       = emb[v * EMB + tid];
        er[tid + 256] = emb[v * EMB + 256 + tid];
        __syncthreads();
        const f4_t* er4 = (const f4_t*)er;
        #pragma unroll
        for (int half = 0; half < 2; ++half) {
            const int o = tid + half * 256;
            const f4_t* wr4 = (const f4_t*)(w_cell + (size_t)o * 1024); // w_x row o
            float s0 = 0.f, s1 = 0.f, s2 = 0.f, s3 = 0.f;
            #pragma unroll 8
            for (int e4 = 0; e4 < 128; ++e4) {
                f4_t w = wr4[e4], a = er4[e4];
                s0 = fmaf(w[0], a[0], s0);
                s1 = fmaf(w[1], a[1], s1);
                s2 = fmaf(w[2], a[2], s2);
                s3 = fmaf(w[3], a[3], s3);
            }
            embp[v * EMB + o] = (s0 + s1) + (s2 + s3) + b_cell[o];
        }
    } else if (blk < 384) {
        // pack w_h[o][e] (= w_cell[o*1024 + 512 + e]) into f16: W2 as u16[o*512+e]
        const int base = (blk - 256) * 1024 + tid;
        #pragma unroll
        for (int i = 0; i < 4; ++i) {
            const int P = base + i * 256;          // 0..131071 (pairs)
            const int o = P >> 8, p = P & 255;
            h2_t v2;
            v2[0] = (_Float16)w_cell[(size_t)o * 1024 + 512 + 2 * p];
            v2[1] = (_Float16)w_cell[(size_t)o * 1024 + 512 + 2 * p + 1];
            W2[P] = __builtin_bit_cast(unsigned, v2);
        }
    } else {
        const int base = (blk - 384) * 2048 + tid;
        #pragma unroll
        for (int i = 0; i < 8; ++i) {
            const int idx = base + i * 256;        // 0..131071
            wh16[idx] = __builtin_bit_cast(u16, (_Float16)w_head[idx]);
        }
    }
}

// ---------------------------------------------------------------------------
// Recurrence, transposed MFMA: h_new^T[512 x 16] = w_h x h^T per step.
// 4 blocks x 512 threads (2 waves/SIMD -> HARD 256 VGPR+AGPR budget/lane).
// w_h split to fit (512 KB = 100% of a CU's RF, full residency impossible):
//   k-slabs 0..11 (384 KB) resident in AGPRs: Af[4][12] = 192 regs/lane.
//   k-slabs 12..15 (128 KB) PERMANENT in LDS (constant), A-frags read per
//   step via stride-1 ds_read_b128 (conflict-free).
// h double-buffered in LDS B-frag order (layout HW-verified R4). 32 KB.
// LDS total = 128 + 32 = 160 KB (dynamic, max).
// Barrier = raw lgkmcnt-only s_barrier (no vmcnt drain); xw gather 1 step
// ahead as MFMA C-init; token 2 ahead; hs stores fire-and-forget.
// ---------------------------------------------------------------------------
__global__ __launch_bounds__(512, 2) void rnn_rec(
    const int* __restrict__ x, const float* __restrict__ h0,
    const u16* __restrict__ whf, const float* __restrict__ embp,
    u16* __restrict__ hs)
{
    extern __shared__ __align__(16) u16 smem[];
    u16* wlds = smem;            // 65536 u16 = 128 KB: frag f=(sp*32+I)*64+lane
    u16* hbuf = smem + 65536;    // [2][8192] u16 = 32 KB, B-frag order

    const int tid  = threadIdx.x;
    const int wave = tid >> 6, lane = tid & 63;
    const int n    = lane & 15, quad = lane >> 4;   // n = batch-in-block
    const int b0   = blockIdx.x * 16;

    // ---- stage w_h k-slabs 12..15 into LDS (one-time, constant) ----
    #pragma unroll
    for (int g = 0; g < 16; ++g) {
        const int f = g * 512 + tid;                // frag id 0..8191
        const int lf = f & 63, If = (f >> 6) & 31, sp = f >> 11;
        const int m = If * 16 + (lf & 15);
        const int k = 384 + sp * 32 + (lf >> 4) * 8;
        *(uint4*)&wlds[(size_t)f * 8] = *(const uint4*)&whf[(size_t)m * 512 + k];
    }

    {   // h0 -> buffer 0, all 16 batch columns (B-frag order)
        const u16 u = __builtin_bit_cast(u16, (_Float16)h0[tid]);
        const int e = tid;
        const int ob = ((e >> 5) * 64 + ((e >> 3) & 3) * 16) * 8 + (e & 7);
        #pragma unroll
        for (int nn = 0; nn < 16; ++nn) hbuf[ob + nn * 8] = u;
    }

    // ---- resident A fragments: rows m = (wave*4+i)*16+n, k-slabs 0..11 ----
    h8_t Af[4][12];
    #pragma unroll
    for (int i = 0; i < 4; ++i)
        #pragma unroll
        for (int s = 0; s < 12; ++s)
            Af[i][s] = *(const h8_t*)&whf[(size_t)(((wave << 2) + i) * 16 + n) * EMB
                                          + s * 32 + quad * 8];

    const int* xp  = x  + (size_t)(b0 + n) * NT;
    u16*       hsp = hs + (size_t)(b0 + n) * NT * EMB;

    int eofs[4], wofs[4];
    #pragma unroll
    for (int i = 0; i < 4; ++i) {
        const int I = (wave << 2) + i;
        eofs[i] = I * 16 + (quad << 2);                       // e-offset of acc[i]
        const int qq = (2 * I + (quad >> 1)) & 3;
        wofs[i] = ((I >> 1) * 64 + qq * 16 + n) * 8 + (quad & 1) * 4;
    }

    __syncthreads();

    int vB = xp[0];
    f4_t xw_cur[4];
    #pragma unroll
    for (int i = 0; i < 4; ++i)
        xw_cur[i] = *(const f4_t*)&embp[(size_t)vB * EMB + eofs[i]];
    vB = xp[1];

    #pragma unroll 1
    for (int t = 0; t < NT; ++t) {
        const int vC = xp[(t + 2 < NT) ? t + 2 : NT - 1];     // token t+2 (clamped)
        f4_t xw_next[4];                                      // xw for t+1, in flight
        #pragma unroll
        for (int i = 0; i < 4; ++i)
            xw_next[i] = *(const f4_t*)&embp[(size_t)vB * EMB + eofs[i]];

        const u16* hb = &hbuf[(t & 1) * 8192];
        f4_t acc[4];
        #pragma unroll
        for (int i = 0; i < 4; ++i) acc[i] = xw_cur[i];       // xw as C-init

        #pragma unroll
        for (int s = 0; s < 12; ++s) {                        // resident slabs
            const h8_t bf = *(const h8_t*)&hb[s * 512 + lane * 8];
            #pragma unroll
            for (int i = 0; i < 4; ++i)
                acc[i] = __builtin_amdgcn_mfma_f32_16x16x32_f16(Af[i][s], bf,
                                                                acc[i], 0, 0, 0);
        }
        #pragma unroll
        for (int sp = 0; sp < 4; ++sp) {                      // LDS-resident slabs
            const h8_t bf = *(const h8_t*)&hb[(12 + sp) * 512 + lane * 8];
            #pragma unroll
            for (int i = 0; i < 4; ++i) {
                const int I = (wave << 2) + i;
                const h8_t af = *(const h8_t*)&wlds[((sp * 32 + I) * 64 + lane) * 8];
                acc[i] = __builtin_amdgcn_mfma_f32_16x16x32_f16(af, bf,
                                                                acc[i], 0, 0, 0);
            }
        }

        u16* hw = &hbuf[((t + 1) & 1) * 8192];
        #pragma unroll
        for (int i = 0; i < 4; ++i) {
            const f4_t a = acc[i];
            uint2 pk;
            pk.x = pk2(fast_tanh(a[0]), fast_tanh(a[1]));
            pk.y = pk2(fast_tanh(a[2]), fast_tanh(a[3]));
            *(uint2*)&hw[wofs[i]] = pk;                       // LDS, B-frag order
            *(uint2*)&hsp[(size_t)t * EMB + eofs[i]] = pk;    // global, no drain
        }

        vB = vC;
        #pragma unroll
        for (int i = 0; i < 4; ++i) xw_cur[i] = xw_next[i];

        // LDS-only barrier: NO vmcnt drain (hs stores / embp gathers fly on)
        asm volatile("s_waitcnt lgkmcnt(0)\n\ts_barrier" ::: "memory");
    }
}

// ---------------------------------------------------------------------------
// Head: out[bt][n] = hs[bt][:] @ w_head[n][:]^T + b_head[n], MFMA f16 16x16x32.
// ---------------------------------------------------------------------------
__global__ __launch_bounds__(512, 2) void head_kernel(
    const u16* __restrict__ hs, const u16* __restrict__ wh16,
    const float* __restrict__ b_head, float* __restrict__ out)
{
    const int tid  = threadIdx.x;
    const int wave = tid >> 6, lane = tid & 63;
    const int l15  = lane & 15, q = lane >> 4;
    const int bt0  = blockIdx.x * 64;

    __shared__ __align__(16) u16 As[64][520];   // +8 halfs pad: breaks bank aliasing

    {   // stage 64x512 f16 tile
        const uint4* src = (const uint4*)(hs + (size_t)bt0 * EMB);
        #pragma unroll
        for (int i = 0; i < 8; ++i) {
            const int idx = tid + i * 512;       // 0..4095 uint4s
            const int row = idx >> 6, col8 = idx & 63;
            *(uint4*)&As[row][col8 * 8] = src[idx];
        }
    }

    // B fragments: wave owns n-tiles {2*wave, 2*wave+1}; B[k][n] = w_head[n][k]
    uint4 bn[16][2];
    #pragma unroll
    for (int i = 0; i < 16; ++i)
        #pragma unroll
        for (int j = 0; j < 2; ++j) {
            const int n = wave * 32 + j * 16 + l15;
            const int k = i * 32 + q * 8;
            bn[i][j] = *(const uint4*)(wh16 + (size_t)n * EMB + k);
        }
    __syncthreads();

    #pragma unroll 1
    for (int mt = 0; mt < 4; ++mt) {
        f4_t acc0 = {0.f, 0.f, 0.f, 0.f}, acc1 = {0.f, 0.f, 0.f, 0.f};
        const int row = mt * 16 + l15;
        #pragma unroll
        for (int i = 0; i < 16; ++i) {
            const int k = i * 32 + q * 8;
            h8_t a = *(const h8_t*)&As[row][k];
            acc0 = __builtin_amdgcn_mfma_f32_16x16x32_f16(
                a, __builtin_bit_cast(h8_t, bn[i][0]), acc0, 0, 0, 0);
            acc1 = __builtin_amdgcn_mfma_f32_16x16x32_f16(
                a, __builtin_bit_cast(h8_t, bn[i][1]), acc1, 0, 0, 0);
        }
        #pragma unroll
        for (int j = 0; j < 2; ++j) {
            const int n = wave * 32 + j * 16 + l15;
            const float bh = b_head[n];
            const f4_t av = j ? acc1 : acc0;
            #pragma unroll
            for (int r = 0; r < 4; ++r) {
                const int orow = bt0 + mt * 16 + q * 4 + r;   // D: row=q*4+r, col=l15
                out[(size_t)orow * VOCAB + n] = av[r] + bh;
            }
        }
    }
}

extern "C" void kernel_launch(void* const* d_in, const int* in_sizes, int n_in,
                              void* d_out, int out_size, void* d_ws, size_t ws_size,
                              hipStream_t stream) {
    (void)in_sizes; (void)n_in; (void)out_size; (void)ws_size;
    const int*   x      = (const int*)  d_in[0];
    const float* emb    = (const float*)d_in[1];
    const float* w_cell = (const float*)d_in[2];
    const float* b_cell = (const float*)d_in[3];
    const float* w_head = (const float*)d_in[4];
    const float* b_head = (const float*)d_in[5];
    const float* h0     = (const float*)d_in[6];
    float* out = (float*)d_out;

    char* ws = (char*)d_ws;
    float*    embp = (float*)   (ws);                 // 256*512*4 = 512 KB
    unsigned* W2   = (unsigned*)(ws + 524288);        // 512*256*4 = 512 KB (f16 w_h)
    u16*      wh16 = (u16*)     (ws + 1048576);       // 256*512*2 = 256 KB
    u16*      hs   = (u16*)     (ws + 1310720);       // 64*1024*512*2 = 64 MB

    // allow 160 KB dynamic LDS (idempotent; same every call -> graph-safe)
    hipFuncSetAttribute((const void*)rnn_rec,
                        hipFuncAttributeMaxDynamicSharedMemorySize, 163840);

    prep_kernel<<<dim3(448), dim3(256), 0, stream>>>(emb, w_cell, b_cell, w_head,
                                                     embp, W2, wh16);
    rnn_rec<<<dim3(4), dim3(512), 163840, stream>>>(x, h0, (const u16*)W2, embp, hs);
    head_kernel<<<dim3((NB * NT) / 64), dim3(512), 0, stream>>>(hs, wh16, b_head, out);
}